// Round 3
// baseline (174.525 us; speedup 1.0000x reference)
//
#include <hip/hip_runtime.h>
#include <math.h>

// S4 DPLR kernel + batched causal convolution via custom packed-real FFTs.
//
//  A) s4_khat_kernel : Y[l] = Hermitian-forced K_hat (fp64, stable Cauchy form,
//       c*inv = 2/(20(1-w) - (1+w)Lambda)); also cot table T[d].
//  B) s4_odd_kernel  : P[l] = sum_d T[d] * Y[(l+d) mod 8192]  (l = 0..4095).
//       Gives the odd bins of H = rfft_16384(pad(irfft_8192(K_hat))):
//         H[2l]   = Y[l]                         (exact, zero-pad identity)
//         H[2l+1] = (S_K + i*P[l]) / 8192        (Dirichlet/half-bin kernel)
//       128 WGs x 256 thr; thread (g,c) = (8-bin group, 128-step d-chunk),
//       8-wide register sliding window; fp64 accumulate; LDS chunk-reduce.
//  C) s4_tab_kernel  : S_K reduce + write sigma-permuted pair tables
//       Ta[m]=H[k(2m)]/8192, Tb[m]=H[8192-k(2m)]/8192 (conv contract unchanged).
//  D) s4_conv_kernel : per batch (1024 WGs, 512 thr, 64KB LDS):
//       pack -> DIF FFT-8192 -> pointwise pair loop -> DIT IFFT -> y.
//       (identical to round 2 — verified)
//
// LDS addresses go through SW(x) = x ^ ((x>>4)&15) to kill bank conflicts.

#define TPB 512

__device__ __forceinline__ int SW(int x){ return x ^ ((x >> 4) & 15); }

__device__ __forceinline__ float2 cadd(float2 a, float2 b){ return make_float2(a.x+b.x, a.y+b.y); }
__device__ __forceinline__ float2 csub(float2 a, float2 b){ return make_float2(a.x-b.x, a.y-b.y); }
__device__ __forceinline__ float2 cmulf(float2 a, float2 b){
  return make_float2(a.x*b.x - a.y*b.y, a.x*b.y + a.y*b.x);
}
template<int SGN>
__device__ __forceinline__ float2 muli(float2 v){
  return (SGN > 0) ? make_float2(-v.y, v.x) : make_float2(v.y, -v.x);
}

template<int SGN>   // -1: forward DFT8; +1: conj (unscaled inverse)
__device__ __forceinline__ void dft8(const float2* a, float2* X){
  const float C  = 0.70710678118654752f;
  const float SC = (SGN > 0) ? C : -C;
  float2 e0=cadd(a[0],a[4]), e1=csub(a[0],a[4]);
  float2 e2=cadd(a[2],a[6]), e3=csub(a[2],a[6]);
  float2 f0=cadd(a[1],a[5]), f1=csub(a[1],a[5]);
  float2 f2=cadd(a[3],a[7]), f3=csub(a[3],a[7]);
  float2 ie3 = muli<SGN>(e3), if3 = muli<SGN>(f3);
  float2 E0=cadd(e0,e2), E2=csub(e0,e2);
  float2 E1=cadd(e1,ie3), E3=csub(e1,ie3);
  float2 O0=cadd(f0,f2), O2=csub(f0,f2);
  float2 O1=cadd(f1,if3), O3=csub(f1,if3);
  float2 O2r = muli<SGN>(O2);
  float2 O1r = cmulf(O1, make_float2(C,  SC));
  float2 O3r = cmulf(O3, make_float2(-C, SC));
  X[0]=cadd(E0,O0);  X[4]=csub(E0,O0);
  X[1]=cadd(E1,O1r); X[5]=csub(E1,O1r);
  X[2]=cadd(E2,O2r); X[6]=csub(E2,O2r);
  X[3]=cadd(E3,O3r); X[7]=csub(E3,O3r);
}

template<int NFFT, int T>
__device__ void dif8_stage(float2* S, int size, int tid){
  const int t = size >> 3;
  const float ang = -6.283185307179586f / (float)size;
  for (int u = tid; u < (NFFT >> 3); u += T){
    int j = u & (t - 1);
    int base = ((u - j) << 3) + j;
    float2 a[8], X[8];
#pragma unroll
    for (int q = 0; q < 8; q++) a[q] = S[SW(base + q*t)];
    dft8<-1>(a, X);
    if (t > 1){
      float sn, cn; __sincosf(ang * (float)j, &sn, &cn);
      float2 w = make_float2(cn, sn), wq = w;
#pragma unroll
      for (int q = 1; q < 8; q++){ X[q] = cmulf(X[q], wq); wq = cmulf(wq, w); }
    }
#pragma unroll
    for (int q = 0; q < 8; q++) S[SW(base + q*t)] = X[q];
  }
}

template<int NFFT, int T>
__device__ void dit8_stage(float2* S, int size, int tid){
  const int t = size >> 3;
  const float ang = 6.283185307179586f / (float)size;
  for (int u = tid; u < (NFFT >> 3); u += T){
    int j = u & (t - 1);
    int base = ((u - j) << 3) + j;
    float2 a[8], X[8];
#pragma unroll
    for (int q = 0; q < 8; q++) a[q] = S[SW(base + q*t)];
    if (t > 1){
      float sn, cn; __sincosf(ang * (float)j, &sn, &cn);
      float2 w = make_float2(cn, sn), wq = w;
#pragma unroll
      for (int q = 1; q < 8; q++){ a[q] = cmulf(a[q], wq); wq = cmulf(wq, w); }
    }
    dft8<1>(a, X);
#pragma unroll
    for (int q = 0; q < 8; q++) S[SW(base + q*t)] = X[q];
  }
}

template<int NFFT, int T>
__device__ void r2_stage(float2* S, int tid){
  float4* S4 = reinterpret_cast<float4*>(S);
  for (int f = tid; f < (NFFT >> 1); f += T){
    int V  = (f >> 3) & 15;
    int fp = f ^ (V >> 1);
    float4 v = S4[fp];
    float sg = (V & 1) ? -1.0f : 1.0f;
    float4 r;
    r.x = sg*v.x + v.z;  r.y = sg*v.y + v.w;
    r.z = v.x - sg*v.z;  r.w = v.y - sg*v.w;
    S4[fp] = r;
  }
}

__device__ __forceinline__ int sig8192(int k){
  return ((k & 7) << 10) | (((k >> 3) & 7) << 7) | (((k >> 6) & 7) << 4)
       | (((k >> 9) & 7) << 1) | ((k >> 12) & 1);
}
__device__ __forceinline__ int siginv_even(int m){  // k such that sig8192(k) == 2m
  return (m >> 9) | (((m >> 6) & 7) << 3) | (((m >> 3) & 7) << 6) | ((m & 7) << 9);
}

// A) K_hat (fp64, all analytic) -> Hermitian-forced Y[0..8191]; cot table T[0..8191]
__global__ __launch_bounds__(256) void s4_khat_kernel(const float* __restrict__ Bp,
                                                      const float* __restrict__ Cp,
                                                      double2* __restrict__ Y,
                                                      double* __restrict__ T){
  const int l = blockIdx.x * blockDim.x + threadIdx.x;   // 0..8191
  const double PI = 3.14159265358979323846264338327950288;
  if (l < 8192){
    double phi = PI * (double)(2*l - 1) / 16384.0;
    double s, c; sincos(phi, &s, &c);
    T[l] = c / s;          // cot(pi*(2d-1)/16384), finite for all d in [0,8192)
  }
  if (l > 4096) return;
  double th = (2.0 * PI / 8192.0) * (double)l;
  double wr = cos(th), wi = sin(th);
  double ux = 1.0 + wr, uy = wi;
  double vx = 1.0 - wr, vy = -wi;
  double gx = 20.0 * vx, gy = 20.0 * vy;
  double s00x=0,s00y=0, s01x=0,s01y=0, s10x=0,s10y=0, s11x=0,s11y=0;
  for (int n = 0; n < 64; n++){
    double Bn = (double)Bp[n], Cn = (double)Cp[n];
    double Pn = sqrt((double)n + 0.5);
    double lx = -0.5, ly = PI * (double)n;
    double dx = gx - (ux*lx - uy*ly);
    double dy = gy - (ux*ly + uy*lx);
    double inv2 = 2.0 / (dx*dx + dy*dy);
    double cix = dx * inv2, ciy = -dy * inv2;
    double w00 = Cn*Bn, w01 = Cn*Pn, w10 = Pn*Bn, w11 = Pn*Pn;
    s00x += w00*cix; s00y += w00*ciy;
    s01x += w01*cix; s01y += w01*ciy;
    s10x += w10*cix; s10y += w10*ciy;
    s11x += w11*cix; s11y += w11*ciy;
  }
  double hux = 0.5*ux, huy = 0.5*uy;
  double k11x = hux*s11x - huy*s11y;
  double k11y = hux*s11y + huy*s11x;
  double p1x = 1.0 + k11x, p1y = k11y;
  double t1x = s01x*p1x - s01y*p1y, t1y = s01x*p1y + s01y*p1x;
  double t2x = t1x*s10x - t1y*s10y, t2y = t1x*s10y + t1y*s10x;
  double crx = t2x*hux - t2y*huy,   cry = t2x*huy + t2y*hux;
  double vr = s00x - crx, vi = s00y - cry;
  // irfft semantics: imag dropped at DC/Nyquist; conj-extend upper half
  if (l == 0)         Y[0]    = make_double2(vr, 0.0);
  else if (l == 4096) Y[4096] = make_double2(vr, 0.0);
  else { Y[l] = make_double2(vr, vi); Y[8192 - l] = make_double2(vr, -vi); }
}

// B) P[l] = sum_{d=0}^{8191} T[d] * Y[(l+d) & 8191], l in [0,4096)
__global__ __launch_bounds__(256) void s4_odd_kernel(const double2* __restrict__ Y,
                                                     const double* __restrict__ T,
                                                     double2* __restrict__ P){
  __shared__ double2 red[256][8];    // 32 KB
  const int tid = threadIdx.x;
  const int g = tid & 3;             // bin group: bins l0+8g .. l0+8g+7
  const int c = tid >> 2;            // d-chunk: d in [128c, 128c+128)
  const int l0 = blockIdx.x * 32;
  const int base = l0 + 8*g + 128*c;
  double2 w[8];
#pragma unroll
  for (int j = 0; j < 8; j++) w[j] = Y[(base + j) & 8191];
  double aR[8] = {0,0,0,0,0,0,0,0};
  double aI[8] = {0,0,0,0,0,0,0,0};
  const double* Tc = T + 128*c;
#pragma unroll 8
  for (int s = 0; s < 128; s++){
    double t = Tc[s];
    double2 nw = Y[(base + s + 8) & 8191];
#pragma unroll
    for (int j = 0; j < 8; j++){ aR[j] += t * w[j].x; aI[j] += t * w[j].y; }
#pragma unroll
    for (int j = 0; j < 7; j++) w[j] = w[j+1];
    w[7] = nw;
  }
#pragma unroll
  for (int j = 0; j < 8; j++) red[tid][j] = make_double2(aR[j], aI[j]);
  __syncthreads();
  if (tid < 32){                     // bin b = tid = 8*(tid>>3) + (tid&7)
    int gg = tid >> 3, j = tid & 7;
    double sr = 0.0, si = 0.0;
    for (int cc = 0; cc < 64; cc++){
      double2 v = red[4*cc + gg][j];
      sr += v.x; si += v.y;
    }
    P[l0 + tid] = make_double2(sr, si);
  }
}

// C) S_K reduce + sigma-permuted pair tables (same contract as round 2 conv)
__global__ __launch_bounds__(1024) void s4_tab_kernel(const double2* __restrict__ Y,
                                                      const double2* __restrict__ P,
                                                      float2* __restrict__ Ta,
                                                      float2* __restrict__ Tb){
  __shared__ double sr_[1024], si_[1024];
  const int tid = threadIdx.x;
  double sr = 0.0, si = 0.0;
  for (int m = tid; m < 8192; m += 1024){ double2 v = Y[m]; sr += v.x; si += v.y; }
  sr_[tid] = sr; si_[tid] = si;
  __syncthreads();
  for (int h = 512; h > 0; h >>= 1){
    if (tid < h){ sr_[tid] += sr_[tid + h]; si_[tid] += si_[tid + h]; }
    __syncthreads();
  }
  const double SKr = sr_[0], SKi = si_[0];
  const double osc = 1.0 / 8192.0;   // odd-bin normalization
  const double sc  = 1.0 / 8192.0;   // inverse-FFT scale folded into tables
  for (int m = tid; m < 4097; m += 1024){
    int k = (m == 4096) ? 4096 : siginv_even(m);
    int f1 = k, f2 = 8192 - k;       // f1,f2 share parity (8192 even)
    double h1r, h1i, h2r, h2i;
    if ((k & 1) == 0){
      double2 a = Y[f1 >> 1]; h1r = a.x; h1i = a.y;     // H[even] = Y exactly
      double2 b = Y[f2 >> 1]; h2r = b.x; h2i = b.y;
    } else {
      double2 p1 = P[(f1 - 1) >> 1];                     // H[odd] = (S_K + i P)/8192
      double2 p2 = P[(f2 - 1) >> 1];
      h1r = (SKr - p1.y) * osc; h1i = (SKi + p1.x) * osc;
      h2r = (SKr - p2.y) * osc; h2i = (SKi + p2.x) * osc;
    }
    Ta[m] = make_float2((float)(h1r * sc), (float)(h1i * sc));
    Tb[m] = make_float2((float)(h2r * sc), (float)(h2i * sc));
  }
}

// D) conv — identical to round 2 (verified)
__global__ __launch_bounds__(TPB, 4) void s4_conv_kernel(const float2* __restrict__ x2,
                                                         const float2* __restrict__ Ta,
                                                         const float2* __restrict__ Tb,
                                                         float2* __restrict__ y2){
  __shared__ __align__(16) float2 S[8192];
  const int tid = threadIdx.x;
  const int b = blockIdx.x;
  const float2* xb = x2 + (size_t)b * 4096;
  for (int n = tid; n < 4096; n += TPB) S[SW(n)] = xb[n];
  for (int n = 4096 + tid; n < 8192; n += TPB) S[n] = make_float2(0.f, 0.f);
  __syncthreads();
  dif8_stage<8192,TPB>(S, 8192, tid); __syncthreads();
  dif8_stage<8192,TPB>(S, 1024, tid); __syncthreads();
  dif8_stage<8192,TPB>(S, 128, tid);  __syncthreads();
  dif8_stage<8192,TPB>(S, 16, tid);   __syncthreads();
  r2_stage<8192,TPB>(S, tid);         __syncthreads();
  for (int m = tid; m < 4097; m += TPB){
    int s, k;
    if (m == 4096){ s = 1; k = 4096; }
    else          { s = 2*m; k = siginv_even(m); }
    int j = (8192 - k) & 8191;
    int sj = sig8192(j);
    int as = SW(s), aj = SW(sj);
    float2 Zk = S[as], Zj = S[aj];
    float2 A  = make_float2(0.5f*(Zk.x + Zj.x), 0.5f*(Zk.y - Zj.y));
    float2 Bc = make_float2(0.5f*(Zk.x - Zj.x), 0.5f*(Zk.y + Zj.y));
    float sn, cn; __sincosf(-3.834951969714103e-4f * (float)k, &sn, &cn);
    float2 tb  = cmulf(make_float2(cn, sn), Bc);
    float2 tcb = cmulf(make_float2(cn, -sn), make_float2(Bc.x, -Bc.y));
    float2 Xk = make_float2(A.x + tb.y,  A.y - tb.x);
    float2 Xm = make_float2(A.x + tcb.y, -A.y - tcb.x);
    float2 Yk = cmulf(Xk, Ta[m]);
    float2 Ym = cmulf(Xm, Tb[m]);
    float2 E = make_float2(0.5f*(Yk.x + Ym.x), 0.5f*(Yk.y - Ym.y));
    float2 D = make_float2(0.5f*(Yk.x - Ym.x), 0.5f*(Yk.y + Ym.y));
    float2 Od = cmulf(make_float2(cn, -sn), D);
    S[as] = make_float2(E.x - Od.y, E.y + Od.x);
    if (aj != as)
      S[aj] = make_float2(E.x + Od.y, Od.x - E.y);
  }
  __syncthreads();
  r2_stage<8192,TPB>(S, tid);         __syncthreads();
  dit8_stage<8192,TPB>(S, 16, tid);   __syncthreads();
  dit8_stage<8192,TPB>(S, 128, tid);  __syncthreads();
  dit8_stage<8192,TPB>(S, 1024, tid); __syncthreads();
  dit8_stage<8192,TPB>(S, 8192, tid); __syncthreads();
  float2* yb = y2 + (size_t)b * 4096;
  for (int n = tid; n < 4096; n += TPB) yb[n] = S[SW(n)];
}

extern "C" void kernel_launch(void* const* d_in, const int* in_sizes, int n_in,
                              void* d_out, int out_size, void* d_ws, size_t ws_size,
                              hipStream_t stream){
  (void)n_in; (void)out_size; (void)ws_size;
  const float* x  = (const float*)d_in[0];
  const float* Bp = (const float*)d_in[1];
  const float* Cp = (const float*)d_in[2];
  // ws: Y[8192] d2 @0 (128K), T[8192] d @131072 (64K), P[4096] d2 @196608 (64K),
  //     Ta[4097] f2 @262144, Tb[4097] f2 @295168  (total ~328 KB)
  double2* Yt = (double2*)d_ws;
  double*  Tt = (double*)((char*)d_ws + 131072);
  double2* Pt = (double2*)((char*)d_ws + 196608);
  float2*  Ta = (float2*)((char*)d_ws + 262144);
  float2*  Tb = (float2*)((char*)d_ws + 295168);
  const int batch = in_sizes[0] / 8192;
  hipLaunchKernelGGL(s4_khat_kernel, dim3(32), dim3(256), 0, stream, Bp, Cp, Yt, Tt);
  hipLaunchKernelGGL(s4_odd_kernel,  dim3(128), dim3(256), 0, stream, Yt, Tt, Pt);
  hipLaunchKernelGGL(s4_tab_kernel,  dim3(1), dim3(1024), 0, stream, Yt, Pt, Ta, Tb);
  hipLaunchKernelGGL(s4_conv_kernel, dim3(batch), dim3(TPB), 0, stream,
                     (const float2*)x, (const float2*)Ta, (const float2*)Tb, (float2*)d_out);
}